// Round 13
// baseline (360.240 us; speedup 1.0000x reference)
//
#include <hip/hip_runtime.h>

// Problem constants (B=64, T=512, I=256, H=512)
#define BATCH 64
#define TSTEPS 512
#define IDIM 256
#define HDIM 512
#define MROWS (BATCH * TSTEPS)   // 32768
#define KZ HDIM                  // zero-row index in W2T (row 512 == 0.0f)

typedef __attribute__((address_space(1))) const void gvoid;
typedef __attribute__((address_space(3))) void lvoid;

__device__ __forceinline__ void gl2lds16(const void* g, void* l) {
    // async global->LDS, 16B per lane; LDS dest = wave-uniform base + lane*16
    __builtin_amdgcn_global_load_lds((gvoid*)g, (lvoid*)l, 16, 0, 0);
}

// ---------------------------------------------------------------------------
// K0: extract center taps: W1T[i][h] = conv1_w[h][i][1] ([k][n] layout);
//                          W2T[h][j] = conv2_w[j][h][1] ([k][n] layout)
// W2T keeps a 513th all-zero row (KZ) — pad target for the sparse layer-2
// kernel; +0.0f adds are bit-neutral (validated absmax 0.0 rounds 1-12).
// ---------------------------------------------------------------------------
__global__ void extract_weights(const float* __restrict__ c1w,
                                const float* __restrict__ c2w,
                                float* __restrict__ W1T,
                                float* __restrict__ W2T) {
    int tid = blockIdx.x * 256 + threadIdx.x;
    if (tid < IDIM * HDIM) {
        int i = tid >> 9;          // / 512
        int h = tid & 511;
        W1T[tid] = c1w[(h * IDIM + i) * 3 + 1];
    }
    if (tid < HDIM * HDIM) {
        int h = tid >> 9;
        int j = tid & 511;
        W2T[tid] = c2w[(j * HDIM + h) * 3 + 1];
    }
    if (tid < HDIM) {
        W2T[HDIM * HDIM + tid] = 0.0f;   // zero pad row
    }
}

// ---------------------------------------------------------------------------
// K1 dense GEMM — ROUND-4 SHAPE VERBATIM (best measured; LDS-pipe floor).
// NUMERICS CONTRACT: each output is ONE sequential fmaf chain, k ascending.
// Used ONLY for layer 1 (x @ W1T, K=256): x is dense Gaussian.
// ---------------------------------------------------------------------------
#define BM 128
#define BN 128
#define BK 16

__global__ __launch_bounds__(256, 2) void gemm_f32(const float* __restrict__ A,
                                                   const float* __restrict__ BT,
                                                   const float* __restrict__ bias,
                                                   float* __restrict__ C,
                                                   int K, int addBias) {
    __shared__ __align__(16) float As[BK * BM];   // [k][m]  8 KB
    __shared__ __align__(16) float Bs[BK * BN];   // [k][n]  8 KB

    const int N = HDIM;
    int tid  = threadIdx.x;
    int lane = tid & 63;
    int wave = tid >> 6;
    int row0 = blockIdx.x * BM;
    int col0 = blockIdx.y * BN;
    int wm = (wave >> 1) * 64;
    int wn = (wave & 1) * 64;
    int mbase = wm + (lane >> 3) * 8;
    int nbase = wn + (lane & 7) * 8;

    float acc[8][8];
#pragma unroll
    for (int i = 0; i < 8; i++)
#pragma unroll
        for (int j = 0; j < 8; j++) acc[i][j] = 0.0f;

    int ar = tid >> 1;
    int ak = (tid & 1) * 8;
    const float* ap = A + (size_t)(row0 + ar) * K + ak;

    const char* bp = (const char*)(BT + (size_t)(tid >> 5) * N + col0) + (tid & 31) * 16;
    char* bld = (char*)Bs + tid * 16;
    const size_t bRow8 = (size_t)8 * N * sizeof(float);

    for (int k0 = 0; k0 < K; k0 += BK) {
        gl2lds16(bp, bld);
        gl2lds16(bp + bRow8, bld + 4096);
        float4 a0 = *(const float4*)(ap);
        float4 a1 = *(const float4*)(ap + 4);
        ap += BK;
        bp += (size_t)BK * N * sizeof(float);
        As[(ak + 0) * BM + ar] = a0.x;
        As[(ak + 1) * BM + ar] = a0.y;
        As[(ak + 2) * BM + ar] = a0.z;
        As[(ak + 3) * BM + ar] = a0.w;
        As[(ak + 4) * BM + ar] = a1.x;
        As[(ak + 5) * BM + ar] = a1.y;
        As[(ak + 6) * BM + ar] = a1.z;
        As[(ak + 7) * BM + ar] = a1.w;
        __syncthreads();

#pragma unroll
        for (int k = 0; k < BK; k++) {
            float4 av0 = *(const float4*)&As[k * BM + mbase];
            float4 av1 = *(const float4*)&As[k * BM + mbase + 4];
            float4 bv0 = *(const float4*)&Bs[k * BN + nbase];
            float4 bv1 = *(const float4*)&Bs[k * BN + nbase + 4];
            float a8[8] = {av0.x, av0.y, av0.z, av0.w, av1.x, av1.y, av1.z, av1.w};
            float b8[8] = {bv0.x, bv0.y, bv0.z, bv0.w, bv1.x, bv1.y, bv1.z, bv1.w};
#pragma unroll
            for (int i = 0; i < 8; i++)
#pragma unroll
                for (int j = 0; j < 8; j++)
                    acc[i][j] = fmaf(a8[i], b8[j], acc[i][j]);
        }
        __syncthreads();
    }

    float bb[8];
#pragma unroll
    for (int j = 0; j < 8; j++)
        bb[j] = addBias ? bias[col0 + nbase + j] : 0.0f;
#pragma unroll
    for (int i = 0; i < 8; i++) {
        int row = row0 + mbase + i;
        float4* cp = (float4*)&C[(size_t)row * N + col0 + nbase];
        cp[0] = (float4){acc[i][0] + bb[0], acc[i][1] + bb[1],
                         acc[i][2] + bb[2], acc[i][3] + bb[3]};
        cp[1] = (float4){acc[i][4] + bb[4], acc[i][5] + bb[5],
                         acc[i][6] + bb[6], acc[i][7] + bb[7]};
    }
}

// ---------------------------------------------------------------------------
// K2 v4: per-(b,h) LIF scan, DEPTH-64 ping-pong + TH==1 fast path.
// Scans are capped at 512 waves (2/CU) — latency hiding is pure ILP. At
// depth-32 each wave held 8 KB in flight vs the ~22 KB/CU latency-BW
// product; depth-64 doubles to 16 KB/wave (32 KB/CU) -> loads fully
// covered. VGPR ~220 is free at 2 waves/CU. Per-element arithmetic chain
// VERBATIM (fast path: IEEE x/1.0 == x bitwise, rounds 10-12 validated;
// general divide path retained). Emits spike BITMASKS (__ballot).
// ---------------------------------------------------------------------------
__global__ __launch_bounds__(64, 1) void lif_scan1(
        const float* __restrict__ z1,
        unsigned long long* __restrict__ masks,
        const float* __restrict__ th_p) {
    int gtid = blockIdx.x * blockDim.x + threadIdx.x;   // 0..32767
    int b = gtid >> 9;
    int h = gtid & 511;
    int lane = threadIdx.x & 63;
    int w = h >> 6;                                     // mask word index 0..7
    float th = *th_p;
    const float* zp = z1 + (size_t)b * TSTEPS * HDIM + h;
    unsigned long long* mp = masks + (size_t)b * TSTEPS * 8 + w;
    float m = 0.0f;
    float bufA[64], bufB[64];
#pragma unroll
    for (int i = 0; i < 64; i++) bufA[i] = zp[(size_t)i * HDIM];
    if (th == 1.0f) {
        // FAST PATH (bit-exact for th==1.0: x/1.0 == x in IEEE RN).
        for (int t0 = 0; t0 < TSTEPS; t0 += 128) {
#pragma unroll
            for (int i = 0; i < 64; i++) bufB[i] = zp[(size_t)(t0 + 64 + i) * HDIM];
#pragma unroll
            for (int i = 0; i < 64; i++) {
                m += bufA[i];
                float thr = m - 1.0f;
                unsigned long long bal = __ballot(thr >= 0.0f);
                if (lane == 0) mp[(size_t)(t0 + i) * 8] = bal;
                if (thr > 0.0f) m -= 1.0f;
            }
            if (t0 + 128 < TSTEPS) {
#pragma unroll
                for (int i = 0; i < 64; i++) bufA[i] = zp[(size_t)(t0 + 128 + i) * HDIM];
            }
#pragma unroll
            for (int i = 0; i < 64; i++) {
                m += bufB[i];
                float thr = m - 1.0f;
                unsigned long long bal = __ballot(thr >= 0.0f);
                if (lane == 0) mp[(size_t)(t0 + 64 + i) * 8] = bal;
                if (thr > 0.0f) m -= 1.0f;
            }
        }
    } else {
        // GENERAL PATH — arithmetic chain VERBATIM (rounds 1-12).
        for (int t0 = 0; t0 < TSTEPS; t0 += 128) {
#pragma unroll
            for (int i = 0; i < 64; i++) bufB[i] = zp[(size_t)(t0 + 64 + i) * HDIM];
#pragma unroll
            for (int i = 0; i < 64; i++) {
                m += bufA[i];
                float thr = m / th - 1.0f;
                unsigned long long bal = __ballot(thr >= 0.0f);
                if (lane == 0) mp[(size_t)(t0 + i) * 8] = bal;
                if (thr > 0.0f) m -= th;
            }
            if (t0 + 128 < TSTEPS) {
#pragma unroll
                for (int i = 0; i < 64; i++) bufA[i] = zp[(size_t)(t0 + 128 + i) * HDIM];
            }
#pragma unroll
            for (int i = 0; i < 64; i++) {
                m += bufB[i];
                float thr = m / th - 1.0f;
                unsigned long long bal = __ballot(thr >= 0.0f);
                if (lane == 0) mp[(size_t)(t0 + 64 + i) * 8] = bal;
                if (thr > 0.0f) m -= th;
            }
        }
    }
}

// ---------------------------------------------------------------------------
// K3 v8 (best measured, ~122 µs — structural floor per rounds 7-9 ledger):
// spike-sparse s1 @ W2T via gl2lds depth-3 pipeline, CH=1, conflict-free
// consume. v9 reg-pipeline failed 3x (compiler re-roll); do not retry.
// Per-output add order strictly k-ascending -> bit-exact.
// ---------------------------------------------------------------------------
#define NBUF 4

__global__ __launch_bounds__(64, 1) void spmm_spikes(
        const unsigned long long* __restrict__ masks,
        const float* __restrict__ W2T,
        float* __restrict__ C) {
    __shared__ __align__(16) float stage[NBUF][HDIM];      // 8 KB
    __shared__ __align__(16) unsigned short klist[512];    // 1 KB
    int lane = threadIdx.x;                                // 1 wave/block
    int m = blockIdx.x;                                    // output row
    const unsigned long long* mrow = masks + (size_t)m * 8;

    // Load all 8 mask words (wave-uniform address -> scalar loads).
    unsigned long long wv[8];
#pragma unroll
    for (int c = 0; c < 8; c++) wv[c] = mrow[c];

    // Wave-parallel k-list build (rounds 1-12 verified): lane l owns bit l of
    // each word; slot = count of set bits below. No padding (CH=1).
    int cnt = 0;
#pragma unroll
    for (int c = 0; c < 8; c++) {
        unsigned long long bal = wv[c];
        int below = (int)__popcll(bal & ((1ull << lane) - 1ull));
        if ((bal >> lane) & 1ull)
            klist[cnt + below] = (unsigned short)((c << 6) | lane);
        cnt += (int)__popcll(bal);
    }
    int nch = __builtin_amdgcn_readfirstlane(cnt);         // chunks of 1 row

    float4 s0 = {0.0f, 0.0f, 0.0f, 0.0f};
    float4 s1 = {0.0f, 0.0f, 0.0f, 0.0f};

    // Stage chunk g (1 W2T row = 2KB) into stage[buf]: 2 x gl2lds16, each
    // 1KB (64 lanes x 16B, linear; rounds 4-12 verified convention).
#define STAGE(buf, g)                                                       \
    {                                                                       \
        unsigned short k_ = klist[g];                                       \
        const float* g0_ = W2T + (size_t)k_ * HDIM + (lane << 2);           \
        float* l_ = &stage[buf][0] + (lane << 2);                           \
        gl2lds16(g0_,       l_);                                            \
        gl2lds16(g0_ + 256, l_ + 256);                                      \
    }

    if (nch > 0) {
        // Drain prologue VMEM so vmcnt counts staging loads only.
        asm volatile("s_waitcnt vmcnt(0)" ::: "memory");
        __builtin_amdgcn_sched_barrier(0);
        STAGE(0, 0);
        if (nch > 1) STAGE(1, 1);
        if (nch > 2) STAGE(2, 2);
        if (nch > 3) STAGE(3, 3);
        for (int g = 0; g < nch; g++) {
            __builtin_amdgcn_sched_barrier(0);
            int rem = nch - 1 - g;                  // chunks still in flight
            if (rem >= 3) {
                asm volatile("s_waitcnt vmcnt(6)" ::: "memory");
            } else if (rem == 2) {
                asm volatile("s_waitcnt vmcnt(4)" ::: "memory");
            } else if (rem == 1) {
                asm volatile("s_waitcnt vmcnt(2)" ::: "memory");
            } else {
                asm volatile("s_waitcnt vmcnt(0)" ::: "memory");
            }
            __builtin_amdgcn_sched_barrier(0);      // rule #18: pin reads below
            const float* base = &stage[g & (NBUF - 1)][0] + (lane << 2);
            float4 w0 = *(const float4*)(base);            // cols 4l..4l+3
            float4 w1 = *(const float4*)(base + 256);      // cols 256+4l..
            s0.x += w0.x; s0.y += w0.y; s0.z += w0.z; s0.w += w0.w;
            s1.x += w1.x; s1.y += w1.y; s1.z += w1.z; s1.w += w1.w;
            __builtin_amdgcn_sched_barrier(0);      // keep consume in its phase
            if (g + NBUF < nch) STAGE(g & (NBUF - 1), g + NBUF);
        }
    }
#undef STAGE

    // lane l writes cols {4l..4l+3} and {256+4l..256+4l+3}: two 1KB stores.
    float* crow = C + (size_t)m * HDIM;
    *(float4*)(crow + (lane << 2))       = s0;
    *(float4*)(crow + 256 + (lane << 2)) = s1;
}

// ---------------------------------------------------------------------------
// K4 v4: per-(b,j) scan, DEPTH-64 ping-pong + TH==1 fast path (same
// rationale and bit-exactness argument as K2 v4). General path VERBATIM.
// ---------------------------------------------------------------------------
__global__ __launch_bounds__(64, 1) void lif_scan2(
        const float* __restrict__ raw,
        const float* __restrict__ b2,
        const float* __restrict__ th_p,
        float* __restrict__ out) {
    int gtid = blockIdx.x * blockDim.x + threadIdx.x;   // 0..32767
    int b = gtid >> 9;
    int j = gtid & 511;
    float th = *th_p;
    float bias = b2[j];
    const float* rp = raw + (size_t)b * TSTEPS * HDIM + j;
    float* op = out + (size_t)b * TSTEPS * HDIM + j;
    float m = 0.0f;
    float bufA[64], bufB[64];
#pragma unroll
    for (int i = 0; i < 64; i++) bufA[i] = rp[(size_t)i * HDIM];
    if (th == 1.0f) {
        // FAST PATH (bit-exact for th==1.0: x/1.0 == x in IEEE RN).
        for (int t0 = 0; t0 < TSTEPS; t0 += 128) {
#pragma unroll
            for (int i = 0; i < 64; i++) bufB[i] = rp[(size_t)(t0 + 64 + i) * HDIM];
            {
                float ss[64];
#pragma unroll
                for (int i = 0; i < 64; i++) {
                    m = (m + bufA[i]) + bias;
                    float thr = m - 1.0f;
                    ss[i] = (thr >= 0.0f) ? 1.0f : 0.0f;
                    if (thr > 0.0f) m -= 1.0f;
                }
#pragma unroll
                for (int i = 0; i < 64; i++) op[(size_t)(t0 + i) * HDIM] = ss[i];
            }
            if (t0 + 128 < TSTEPS) {
#pragma unroll
                for (int i = 0; i < 64; i++) bufA[i] = rp[(size_t)(t0 + 128 + i) * HDIM];
            }
            {
                float ss[64];
#pragma unroll
                for (int i = 0; i < 64; i++) {
                    m = (m + bufB[i]) + bias;
                    float thr = m - 1.0f;
                    ss[i] = (thr >= 0.0f) ? 1.0f : 0.0f;
                    if (thr > 0.0f) m -= 1.0f;
                }
#pragma unroll
                for (int i = 0; i < 64; i++) op[(size_t)(t0 + 64 + i) * HDIM] = ss[i];
            }
        }
    } else {
        // GENERAL PATH — arithmetic chain VERBATIM (rounds 1-12).
        for (int t0 = 0; t0 < TSTEPS; t0 += 128) {
#pragma unroll
            for (int i = 0; i < 64; i++) bufB[i] = rp[(size_t)(t0 + 64 + i) * HDIM];
            {
                float ss[64];
#pragma unroll
                for (int i = 0; i < 64; i++) {
                    m = (m + bufA[i]) + bias;
                    float thr = m / th - 1.0f;
                    ss[i] = (thr >= 0.0f) ? 1.0f : 0.0f;
                    if (thr > 0.0f) m -= th;
                }
#pragma unroll
                for (int i = 0; i < 64; i++) op[(size_t)(t0 + i) * HDIM] = ss[i];
            }
            if (t0 + 128 < TSTEPS) {
#pragma unroll
                for (int i = 0; i < 64; i++) bufA[i] = rp[(size_t)(t0 + 128 + i) * HDIM];
            }
            {
                float ss[64];
#pragma unroll
                for (int i = 0; i < 64; i++) {
                    m = (m + bufB[i]) + bias;
                    float thr = m / th - 1.0f;
                    ss[i] = (thr >= 0.0f) ? 1.0f : 0.0f;
                    if (thr > 0.0f) m -= th;
                }
#pragma unroll
                for (int i = 0; i < 64; i++) op[(size_t)(t0 + 64 + i) * HDIM] = ss[i];
            }
        }
    }
}

// ---------------------------------------------------------------------------
extern "C" void kernel_launch(void* const* d_in, const int* in_sizes, int n_in,
                              void* d_out, int out_size, void* d_ws, size_t ws_size,
                              hipStream_t stream) {
    const float* x    = (const float*)d_in[0];   // (64, 512, 256)
    const float* c1w  = (const float*)d_in[1];   // (512, 256, 3)
    const float* c1b  = (const float*)d_in[2];   // (512,)
    const float* c2w  = (const float*)d_in[3];   // (512, 512, 3)
    const float* c2b  = (const float*)d_in[4];   // (512,)
    const float* th1  = (const float*)d_in[5];   // scalar
    const float* th2  = (const float*)d_in[6];   // scalar
    float* out = (float*)d_out;                  // (64, 512, 512)

    // Workspace layout (floats):
    //   W1T  : 131072     (512 KB)  [k=i][n=h]
    //   W2T  : 513*512    (~1 MB)   [k=h][n=j] + zero pad row at k=512
    //   bufA : 16777216   (64 MB)   z1, later z2raw  [m][n]
    //   masks: 32768*8 u64 (2 MB)   spike bitmasks   [m][kword]
    float* W1T  = (float*)d_ws;
    float* W2T  = W1T + IDIM * HDIM;
    float* bufA = W2T + (HDIM + 1) * HDIM;
    unsigned long long* masks = (unsigned long long*)(bufA + (size_t)MROWS * HDIM);

    // K0: weight extraction (+ zero pad row)
    extract_weights<<<(HDIM * HDIM + 255) / 256, 256, 0, stream>>>(c1w, c2w, W1T, W2T);

    // K1: z1 = x @ W1T + b1   (M=32768, K=256, N=512) -> bufA
    {
        dim3 grid(MROWS / BM, HDIM / BN);
        gemm_f32<<<grid, 256, 0, stream>>>(x, W1T, c1b, bufA, IDIM, 1);
    }

    // K2: s1 scan -> spike bitmasks (no float s1 materialization)
    lif_scan1<<<MROWS / 64, 64, 0, stream>>>(bufA, masks, th1);

    // K3: z2raw[m][:] = sum_{k in spikes(m)} W2T[k][:]  (bit-exact sparse)
    spmm_spikes<<<MROWS, 64, 0, stream>>>(masks, W2T, bufA);

    // K4: s2 scan -> out
    lif_scan2<<<MROWS / 64, 64, 0, stream>>>(bufA, c2b, th2, out);
}

// Round 14
// 348.878 us; speedup vs baseline: 1.0326x; 1.0326x over previous
//
#include <hip/hip_runtime.h>

// Problem constants (B=64, T=512, I=256, H=512)
#define BATCH 64
#define TSTEPS 512
#define IDIM 256
#define HDIM 512
#define MROWS (BATCH * TSTEPS)   // 32768
#define KZ HDIM                  // zero-row index in W2T (row 512 == 0.0f)

typedef __attribute__((address_space(1))) const void gvoid;
typedef __attribute__((address_space(3))) void lvoid;

__device__ __forceinline__ void gl2lds16(const void* g, void* l) {
    // async global->LDS, 16B per lane; LDS dest = wave-uniform base + lane*16
    __builtin_amdgcn_global_load_lds((gvoid*)g, (lvoid*)l, 16, 0, 0);
}

// ---------------------------------------------------------------------------
// K0: extract center taps: W1T[i][h] = conv1_w[h][i][1] ([k][n] layout);
//                          W2T[h][j] = conv2_w[j][h][1] ([k][n] layout)
// W2T keeps a 513th all-zero row (KZ) — pad target for the sparse layer-2
// kernel; +0.0f adds are bit-neutral (validated absmax 0.0 rounds 1-13).
// ---------------------------------------------------------------------------
__global__ void extract_weights(const float* __restrict__ c1w,
                                const float* __restrict__ c2w,
                                float* __restrict__ W1T,
                                float* __restrict__ W2T) {
    int tid = blockIdx.x * 256 + threadIdx.x;
    if (tid < IDIM * HDIM) {
        int i = tid >> 9;          // / 512
        int h = tid & 511;
        W1T[tid] = c1w[(h * IDIM + i) * 3 + 1];
    }
    if (tid < HDIM * HDIM) {
        int h = tid >> 9;
        int j = tid & 511;
        W2T[tid] = c2w[(j * HDIM + h) * 3 + 1];
    }
    if (tid < HDIM) {
        W2T[HDIM * HDIM + tid] = 0.0f;   // zero pad row
    }
}

// ---------------------------------------------------------------------------
// K1 dense GEMM — ROUND-4 SHAPE VERBATIM (best measured; LDS-pipe floor).
// NUMERICS CONTRACT: each output is ONE sequential fmaf chain, k ascending.
// Used ONLY for layer 1 (x @ W1T, K=256): x is dense Gaussian.
// ---------------------------------------------------------------------------
#define BM 128
#define BN 128
#define BK 16

__global__ __launch_bounds__(256, 2) void gemm_f32(const float* __restrict__ A,
                                                   const float* __restrict__ BT,
                                                   const float* __restrict__ bias,
                                                   float* __restrict__ C,
                                                   int K, int addBias) {
    __shared__ __align__(16) float As[BK * BM];   // [k][m]  8 KB
    __shared__ __align__(16) float Bs[BK * BN];   // [k][n]  8 KB

    const int N = HDIM;
    int tid  = threadIdx.x;
    int lane = tid & 63;
    int wave = tid >> 6;
    int row0 = blockIdx.x * BM;
    int col0 = blockIdx.y * BN;
    int wm = (wave >> 1) * 64;
    int wn = (wave & 1) * 64;
    int mbase = wm + (lane >> 3) * 8;
    int nbase = wn + (lane & 7) * 8;

    float acc[8][8];
#pragma unroll
    for (int i = 0; i < 8; i++)
#pragma unroll
        for (int j = 0; j < 8; j++) acc[i][j] = 0.0f;

    int ar = tid >> 1;
    int ak = (tid & 1) * 8;
    const float* ap = A + (size_t)(row0 + ar) * K + ak;

    const char* bp = (const char*)(BT + (size_t)(tid >> 5) * N + col0) + (tid & 31) * 16;
    char* bld = (char*)Bs + tid * 16;
    const size_t bRow8 = (size_t)8 * N * sizeof(float);

    for (int k0 = 0; k0 < K; k0 += BK) {
        gl2lds16(bp, bld);
        gl2lds16(bp + bRow8, bld + 4096);
        float4 a0 = *(const float4*)(ap);
        float4 a1 = *(const float4*)(ap + 4);
        ap += BK;
        bp += (size_t)BK * N * sizeof(float);
        As[(ak + 0) * BM + ar] = a0.x;
        As[(ak + 1) * BM + ar] = a0.y;
        As[(ak + 2) * BM + ar] = a0.z;
        As[(ak + 3) * BM + ar] = a0.w;
        As[(ak + 4) * BM + ar] = a1.x;
        As[(ak + 5) * BM + ar] = a1.y;
        As[(ak + 6) * BM + ar] = a1.z;
        As[(ak + 7) * BM + ar] = a1.w;
        __syncthreads();

#pragma unroll
        for (int k = 0; k < BK; k++) {
            float4 av0 = *(const float4*)&As[k * BM + mbase];
            float4 av1 = *(const float4*)&As[k * BM + mbase + 4];
            float4 bv0 = *(const float4*)&Bs[k * BN + nbase];
            float4 bv1 = *(const float4*)&Bs[k * BN + nbase + 4];
            float a8[8] = {av0.x, av0.y, av0.z, av0.w, av1.x, av1.y, av1.z, av1.w};
            float b8[8] = {bv0.x, bv0.y, bv0.z, bv0.w, bv1.x, bv1.y, bv1.z, bv1.w};
#pragma unroll
            for (int i = 0; i < 8; i++)
#pragma unroll
                for (int j = 0; j < 8; j++)
                    acc[i][j] = fmaf(a8[i], b8[j], acc[i][j]);
        }
        __syncthreads();
    }

    float bb[8];
#pragma unroll
    for (int j = 0; j < 8; j++)
        bb[j] = addBias ? bias[col0 + nbase + j] : 0.0f;
#pragma unroll
    for (int i = 0; i < 8; i++) {
        int row = row0 + mbase + i;
        float4* cp = (float4*)&C[(size_t)row * N + col0 + nbase];
        cp[0] = (float4){acc[i][0] + bb[0], acc[i][1] + bb[1],
                         acc[i][2] + bb[2], acc[i][3] + bb[3]};
        cp[1] = (float4){acc[i][4] + bb[4], acc[i][5] + bb[5],
                         acc[i][6] + bb[6], acc[i][7] + bb[7]};
    }
}

// ---------------------------------------------------------------------------
// K2 v3 (round-12 optimum, RESTORED): per-(b,h) LIF scan, depth-32 ping-pong
// + TH==1 fast path. Round-13 post-mortem: depth-64 regressed (+11 µs —
// VGPR pressure at the 256 boundary + exposed 64-load prologue; depth-32
// already covers the ~900cy HBM latency). Per-element arithmetic chain
// VERBATIM (fast path: IEEE x/1.0 == x bitwise, rounds 10-13 validated;
// general divide path retained). Emits spike BITMASKS (__ballot).
// ---------------------------------------------------------------------------
__global__ __launch_bounds__(64, 1) void lif_scan1(
        const float* __restrict__ z1,
        unsigned long long* __restrict__ masks,
        const float* __restrict__ th_p) {
    int gtid = blockIdx.x * blockDim.x + threadIdx.x;   // 0..32767
    int b = gtid >> 9;
    int h = gtid & 511;
    int lane = threadIdx.x & 63;
    int w = h >> 6;                                     // mask word index 0..7
    float th = *th_p;
    const float* zp = z1 + (size_t)b * TSTEPS * HDIM + h;
    unsigned long long* mp = masks + (size_t)b * TSTEPS * 8 + w;
    float m = 0.0f;
    float bufA[32], bufB[32];
#pragma unroll
    for (int i = 0; i < 32; i++) bufA[i] = zp[(size_t)i * HDIM];
    if (th == 1.0f) {
        // FAST PATH (bit-exact for th==1.0: x/1.0 == x in IEEE RN).
        for (int t0 = 0; t0 < TSTEPS; t0 += 64) {
#pragma unroll
            for (int i = 0; i < 32; i++) bufB[i] = zp[(size_t)(t0 + 32 + i) * HDIM];
#pragma unroll
            for (int i = 0; i < 32; i++) {
                m += bufA[i];
                float thr = m - 1.0f;
                unsigned long long bal = __ballot(thr >= 0.0f);
                if (lane == 0) mp[(size_t)(t0 + i) * 8] = bal;
                if (thr > 0.0f) m -= 1.0f;
            }
            if (t0 + 64 < TSTEPS) {
#pragma unroll
                for (int i = 0; i < 32; i++) bufA[i] = zp[(size_t)(t0 + 64 + i) * HDIM];
            }
#pragma unroll
            for (int i = 0; i < 32; i++) {
                m += bufB[i];
                float thr = m - 1.0f;
                unsigned long long bal = __ballot(thr >= 0.0f);
                if (lane == 0) mp[(size_t)(t0 + 32 + i) * 8] = bal;
                if (thr > 0.0f) m -= 1.0f;
            }
        }
    } else {
        // GENERAL PATH — arithmetic chain VERBATIM (rounds 1-12).
        for (int t0 = 0; t0 < TSTEPS; t0 += 64) {
#pragma unroll
            for (int i = 0; i < 32; i++) bufB[i] = zp[(size_t)(t0 + 32 + i) * HDIM];
#pragma unroll
            for (int i = 0; i < 32; i++) {
                m += bufA[i];
                float thr = m / th - 1.0f;
                unsigned long long bal = __ballot(thr >= 0.0f);
                if (lane == 0) mp[(size_t)(t0 + i) * 8] = bal;
                if (thr > 0.0f) m -= th;
            }
            if (t0 + 64 < TSTEPS) {
#pragma unroll
                for (int i = 0; i < 32; i++) bufA[i] = zp[(size_t)(t0 + 64 + i) * HDIM];
            }
#pragma unroll
            for (int i = 0; i < 32; i++) {
                m += bufB[i];
                float thr = m / th - 1.0f;
                unsigned long long bal = __ballot(thr >= 0.0f);
                if (lane == 0) mp[(size_t)(t0 + 32 + i) * 8] = bal;
                if (thr > 0.0f) m -= th;
            }
        }
    }
}

// ---------------------------------------------------------------------------
// K3 v8 (best measured, ~122 µs — structural floor per rounds 7-9 ledger):
// spike-sparse s1 @ W2T via gl2lds depth-3 pipeline, CH=1, conflict-free
// consume. v9 reg-pipeline failed 3x (compiler re-roll); do not retry.
// Per-output add order strictly k-ascending -> bit-exact.
// ---------------------------------------------------------------------------
#define NBUF 4

__global__ __launch_bounds__(64, 1) void spmm_spikes(
        const unsigned long long* __restrict__ masks,
        const float* __restrict__ W2T,
        float* __restrict__ C) {
    __shared__ __align__(16) float stage[NBUF][HDIM];      // 8 KB
    __shared__ __align__(16) unsigned short klist[512];    // 1 KB
    int lane = threadIdx.x;                                // 1 wave/block
    int m = blockIdx.x;                                    // output row
    const unsigned long long* mrow = masks + (size_t)m * 8;

    // Load all 8 mask words (wave-uniform address -> scalar loads).
    unsigned long long wv[8];
#pragma unroll
    for (int c = 0; c < 8; c++) wv[c] = mrow[c];

    // Wave-parallel k-list build (rounds 1-13 verified): lane l owns bit l of
    // each word; slot = count of set bits below. No padding (CH=1).
    int cnt = 0;
#pragma unroll
    for (int c = 0; c < 8; c++) {
        unsigned long long bal = wv[c];
        int below = (int)__popcll(bal & ((1ull << lane) - 1ull));
        if ((bal >> lane) & 1ull)
            klist[cnt + below] = (unsigned short)((c << 6) | lane);
        cnt += (int)__popcll(bal);
    }
    int nch = __builtin_amdgcn_readfirstlane(cnt);         // chunks of 1 row

    float4 s0 = {0.0f, 0.0f, 0.0f, 0.0f};
    float4 s1 = {0.0f, 0.0f, 0.0f, 0.0f};

    // Stage chunk g (1 W2T row = 2KB) into stage[buf]: 2 x gl2lds16, each
    // 1KB (64 lanes x 16B, linear; rounds 4-13 verified convention).
#define STAGE(buf, g)                                                       \
    {                                                                       \
        unsigned short k_ = klist[g];                                       \
        const float* g0_ = W2T + (size_t)k_ * HDIM + (lane << 2);           \
        float* l_ = &stage[buf][0] + (lane << 2);                           \
        gl2lds16(g0_,       l_);                                            \
        gl2lds16(g0_ + 256, l_ + 256);                                      \
    }

    if (nch > 0) {
        // Drain prologue VMEM so vmcnt counts staging loads only.
        asm volatile("s_waitcnt vmcnt(0)" ::: "memory");
        __builtin_amdgcn_sched_barrier(0);
        STAGE(0, 0);
        if (nch > 1) STAGE(1, 1);
        if (nch > 2) STAGE(2, 2);
        if (nch > 3) STAGE(3, 3);
        for (int g = 0; g < nch; g++) {
            __builtin_amdgcn_sched_barrier(0);
            int rem = nch - 1 - g;                  // chunks still in flight
            if (rem >= 3) {
                asm volatile("s_waitcnt vmcnt(6)" ::: "memory");
            } else if (rem == 2) {
                asm volatile("s_waitcnt vmcnt(4)" ::: "memory");
            } else if (rem == 1) {
                asm volatile("s_waitcnt vmcnt(2)" ::: "memory");
            } else {
                asm volatile("s_waitcnt vmcnt(0)" ::: "memory");
            }
            __builtin_amdgcn_sched_barrier(0);      // rule #18: pin reads below
            const float* base = &stage[g & (NBUF - 1)][0] + (lane << 2);
            float4 w0 = *(const float4*)(base);            // cols 4l..4l+3
            float4 w1 = *(const float4*)(base + 256);      // cols 256+4l..
            s0.x += w0.x; s0.y += w0.y; s0.z += w0.z; s0.w += w0.w;
            s1.x += w1.x; s1.y += w1.y; s1.z += w1.z; s1.w += w1.w;
            __builtin_amdgcn_sched_barrier(0);      // keep consume in its phase
            if (g + NBUF < nch) STAGE(g & (NBUF - 1), g + NBUF);
        }
    }
#undef STAGE

    // lane l writes cols {4l..4l+3} and {256+4l..256+4l+3}: two 1KB stores.
    float* crow = C + (size_t)m * HDIM;
    *(float4*)(crow + (lane << 2))       = s0;
    *(float4*)(crow + 256 + (lane << 2)) = s1;
}

// ---------------------------------------------------------------------------
// K4 v3 (round-12 optimum, RESTORED): per-(b,j) scan, depth-32 ping-pong +
// TH==1 fast path (same rationale/bit-exactness as K2). General path VERBATIM.
// ---------------------------------------------------------------------------
__global__ __launch_bounds__(64, 1) void lif_scan2(
        const float* __restrict__ raw,
        const float* __restrict__ b2,
        const float* __restrict__ th_p,
        float* __restrict__ out) {
    int gtid = blockIdx.x * blockDim.x + threadIdx.x;   // 0..32767
    int b = gtid >> 9;
    int j = gtid & 511;
    float th = *th_p;
    float bias = b2[j];
    const float* rp = raw + (size_t)b * TSTEPS * HDIM + j;
    float* op = out + (size_t)b * TSTEPS * HDIM + j;
    float m = 0.0f;
    float bufA[32], bufB[32];
#pragma unroll
    for (int i = 0; i < 32; i++) bufA[i] = rp[(size_t)i * HDIM];
    if (th == 1.0f) {
        // FAST PATH (bit-exact for th==1.0: x/1.0 == x in IEEE RN).
        for (int t0 = 0; t0 < TSTEPS; t0 += 64) {
#pragma unroll
            for (int i = 0; i < 32; i++) bufB[i] = rp[(size_t)(t0 + 32 + i) * HDIM];
            {
                float ss[32];
#pragma unroll
                for (int i = 0; i < 32; i++) {
                    m = (m + bufA[i]) + bias;
                    float thr = m - 1.0f;
                    ss[i] = (thr >= 0.0f) ? 1.0f : 0.0f;
                    if (thr > 0.0f) m -= 1.0f;
                }
#pragma unroll
                for (int i = 0; i < 32; i++) op[(size_t)(t0 + i) * HDIM] = ss[i];
            }
            if (t0 + 64 < TSTEPS) {
#pragma unroll
                for (int i = 0; i < 32; i++) bufA[i] = rp[(size_t)(t0 + 64 + i) * HDIM];
            }
            {
                float ss[32];
#pragma unroll
                for (int i = 0; i < 32; i++) {
                    m = (m + bufB[i]) + bias;
                    float thr = m - 1.0f;
                    ss[i] = (thr >= 0.0f) ? 1.0f : 0.0f;
                    if (thr > 0.0f) m -= 1.0f;
                }
#pragma unroll
                for (int i = 0; i < 32; i++) op[(size_t)(t0 + 32 + i) * HDIM] = ss[i];
            }
        }
    } else {
        // GENERAL PATH — arithmetic chain VERBATIM (rounds 1-12).
        for (int t0 = 0; t0 < TSTEPS; t0 += 64) {
#pragma unroll
            for (int i = 0; i < 32; i++) bufB[i] = rp[(size_t)(t0 + 32 + i) * HDIM];
            {
                float ss[32];
#pragma unroll
                for (int i = 0; i < 32; i++) {
                    m = (m + bufA[i]) + bias;
                    float thr = m / th - 1.0f;
                    ss[i] = (thr >= 0.0f) ? 1.0f : 0.0f;
                    if (thr > 0.0f) m -= th;
                }
#pragma unroll
                for (int i = 0; i < 32; i++) op[(size_t)(t0 + i) * HDIM] = ss[i];
            }
            if (t0 + 64 < TSTEPS) {
#pragma unroll
                for (int i = 0; i < 32; i++) bufA[i] = rp[(size_t)(t0 + 64 + i) * HDIM];
            }
            {
                float ss[32];
#pragma unroll
                for (int i = 0; i < 32; i++) {
                    m = (m + bufB[i]) + bias;
                    float thr = m / th - 1.0f;
                    ss[i] = (thr >= 0.0f) ? 1.0f : 0.0f;
                    if (thr > 0.0f) m -= th;
                }
#pragma unroll
                for (int i = 0; i < 32; i++) op[(size_t)(t0 + 32 + i) * HDIM] = ss[i];
            }
        }
    }
}

// ---------------------------------------------------------------------------
extern "C" void kernel_launch(void* const* d_in, const int* in_sizes, int n_in,
                              void* d_out, int out_size, void* d_ws, size_t ws_size,
                              hipStream_t stream) {
    const float* x    = (const float*)d_in[0];   // (64, 512, 256)
    const float* c1w  = (const float*)d_in[1];   // (512, 256, 3)
    const float* c1b  = (const float*)d_in[2];   // (512,)
    const float* c2w  = (const float*)d_in[3];   // (512, 512, 3)
    const float* c2b  = (const float*)d_in[4];   // (512,)
    const float* th1  = (const float*)d_in[5];   // scalar
    const float* th2  = (const float*)d_in[6];   // scalar
    float* out = (float*)d_out;                  // (64, 512, 512)

    // Workspace layout (floats):
    //   W1T  : 131072     (512 KB)  [k=i][n=h]
    //   W2T  : 513*512    (~1 MB)   [k=h][n=j] + zero pad row at k=512
    //   bufA : 16777216   (64 MB)   z1, later z2raw  [m][n]
    //   masks: 32768*8 u64 (2 MB)   spike bitmasks   [m][kword]
    float* W1T  = (float*)d_ws;
    float* W2T  = W1T + IDIM * HDIM;
    float* bufA = W2T + (HDIM + 1) * HDIM;
    unsigned long long* masks = (unsigned long long*)(bufA + (size_t)MROWS * HDIM);

    // K0: weight extraction (+ zero pad row)
    extract_weights<<<(HDIM * HDIM + 255) / 256, 256, 0, stream>>>(c1w, c2w, W1T, W2T);

    // K1: z1 = x @ W1T + b1   (M=32768, K=256, N=512) -> bufA
    {
        dim3 grid(MROWS / BM, HDIM / BN);
        gemm_f32<<<grid, 256, 0, stream>>>(x, W1T, c1b, bufA, IDIM, 1);
    }

    // K2: s1 scan -> spike bitmasks (no float s1 materialization)
    lif_scan1<<<MROWS / 64, 64, 0, stream>>>(bufA, masks, th1);

    // K3: z2raw[m][:] = sum_{k in spikes(m)} W2T[k][:]  (bit-exact sparse)
    spmm_spikes<<<MROWS, 64, 0, stream>>>(masks, W2T, bufA);

    // K4: s2 scan -> out
    lif_scan2<<<MROWS / 64, 64, 0, stream>>>(bufA, c2b, th2, out);
}